// Round 3
// baseline (805.253 us; speedup 1.0000x reference)
//
#include <hip/hip_runtime.h>
#include <hip/hip_bf16.h>
#include <cstdint>
#include <cstdio>

typedef unsigned short ushort_t;
typedef __attribute__((ext_vector_type(8))) __bf16 bf16x8;
typedef __attribute__((ext_vector_type(2))) __bf16 bhalf2_t;
typedef __attribute__((ext_vector_type(8))) unsigned short us8;
typedef __attribute__((ext_vector_type(4))) unsigned short us4;
typedef __attribute__((ext_vector_type(4))) float f32x4;
typedef __attribute__((ext_vector_type(2))) float f32x2;

__device__ __forceinline__ ushort_t f2b(float f) {
  uint32_t u = __builtin_bit_cast(uint32_t, f);
  uint32_t r = (u + 0x7fffu + ((u >> 16) & 1u)) >> 16;  // RNE
  return (ushort_t)r;
}
__device__ __forceinline__ float b2f(ushort_t s) {
  return __builtin_bit_cast(float, (uint32_t)s << 16);
}

// async global->LDS, 16B per lane; LDS dest = wave-uniform base + lane*16
__device__ __forceinline__ void gld_lds16(const void* g, void* l) {
  __builtin_amdgcn_global_load_lds(
      (__attribute__((address_space(1))) void*)(uintptr_t)g,
      (__attribute__((address_space(3))) void*)(uint32_t)(uintptr_t)l,
      16, 0, 0);
}

// ---------- cast fp32 -> bf16, 4 elems/thread ----------
__global__ void cast_f2b(const float* __restrict__ src, ushort_t* __restrict__ dst, int n4) {
  int i = blockIdx.x * 256 + threadIdx.x;
  if (i < n4) {
    float4 f = ((const float4*)src)[i];
    us4 o = { f2b(f.x), f2b(f.y), f2b(f.z), f2b(f.w) };
    ((us4*)dst)[i] = o;
  }
}

// ---------- cast 3 weight matrices (wq,wk,wv) into contiguous dst ----------
__global__ void cast3_f2b(const float* __restrict__ a, const float* __restrict__ b,
                          const float* __restrict__ c, ushort_t* __restrict__ dst) {
  int i = blockIdx.x * 256 + threadIdx.x;  // float4 index, 3*1048576 total
  int seg = i >> 20, local = i & 1048575;
  const float* src = (seg == 0) ? a : (seg == 1) ? b : c;
  float4 f = ((const float4*)src)[local];
  us4 o = { f2b(f.x), f2b(f.y), f2b(f.z), f2b(f.w) };
  ((us4*)dst)[i] = o;
}

// ---------- GEMM: C[m,n] = sum_k A[m,k]*B[n,k]; A:[M,K] B:[N,K] row-major bf16 ----------
// 256x256 tile, BK=64, 8 waves (2Mx4N), double-buffered LDS (128 KiB, 1 block/CU).
// m201-style 8-phase schedule with COUNTED vmcnt (T3+T4): raw s_barrier (no
// compiler vmcnt(0) drain), per-phase {12 ds_read_b128, half-tile DMA issue,
// barrier, setprio, 16 MFMA, setprio, barrier}. Half-tile = 128 rows of one
// matrix (2 gld_lds/wave). B-halves of tile t+1 issued in phases 0/1 of tile t;
// A-halves of tile t+2 issued at the boundary into the freed buffer, then
// s_waitcnt vmcnt(4): >=2 half-tiles stay in flight across every barrier.
// Chunk-XOR swizzle (T2): LDS[row][c] = global[row][c ^ (row&7)] in 8-elem
// chunks, conflict-free ds_read_b128. Buffers are 4 distinct static arrays with
// compile-time selection (2x-unrolled tile loop) so waitcnt insertion can
// disambiguate DMA writes (next buffer) from ds_reads (current buffer).
// Hang-audit (round 3): uniform barriers, per-wave vmcnt ledger verified for
// prologue / steady state / final pair, LDS rows <=255, global addrs in bounds.
#define GEMM_PHASE(Asc, Bsc, MH, NH, STAGE)                                          \
  do {                                                                               \
    bf16x8 af[2][4], bg[2][2];                                                       \
    _Pragma("unroll")                                                                \
    for (int kk = 0; kk < 2; ++kk) {                                                 \
      const int cx = ((kk * 4 + quad) ^ (m_l & 7)) * 8;                              \
      _Pragma("unroll")                                                              \
      for (int mt = 0; mt < 4; ++mt)                                                 \
        af[kk][mt] = __builtin_bit_cast(bf16x8,                                      \
            *(const us8*)&Asc[(wr + ((MH) * 4 + mt) * 16 + m_l) * 64 + cx]);         \
      _Pragma("unroll")                                                              \
      for (int nt = 0; nt < 2; ++nt)                                                 \
        bg[kk][nt] = __builtin_bit_cast(bf16x8,                                      \
            *(const us8*)&Bsc[(wc + ((NH) * 2 + nt) * 16 + m_l) * 64 + cx]);         \
    }                                                                                \
    STAGE;                                                                           \
    __builtin_amdgcn_s_barrier();                                                    \
    __builtin_amdgcn_s_setprio(1);                                                   \
    _Pragma("unroll")                                                                \
    for (int kk = 0; kk < 2; ++kk)                                                   \
      _Pragma("unroll")                                                              \
      for (int mt = 0; mt < 4; ++mt)                                                 \
        _Pragma("unroll")                                                            \
        for (int nt = 0; nt < 2; ++nt)                                               \
          acc[(MH) * 4 + mt][(NH) * 2 + nt] = __builtin_amdgcn_mfma_f32_16x16x32_bf16( \
              af[kk][mt], bg[kk][nt], acc[(MH) * 4 + mt][(NH) * 2 + nt], 0, 0, 0);   \
    __builtin_amdgcn_s_setprio(0);                                                   \
    __builtin_amdgcn_s_barrier();                                                    \
  } while (0)

template <typename OutT>
__global__ __launch_bounds__(512, 2) void gemm_bt(const ushort_t* __restrict__ A,
                                                  const ushort_t* __restrict__ B,
                                                  OutT* __restrict__ C,
                                                  int M, int N, int K) {
  __shared__ ushort_t As0[256 * 64], As1[256 * 64];
  __shared__ ushort_t Bs0[256 * 64], Bs1[256 * 64];
  const int w    = threadIdx.x >> 6;
  const int lane = threadIdx.x & 63;
  const int m_l  = lane & 15;
  const int quad = lane >> 4;
  const int m0 = blockIdx.y * 256, n0 = blockIdx.x * 256;
  const int wr = (w >> 2) * 128, wc = (w & 3) * 64;  // per-wave 128x64 output

  f32x4 acc[8][4];
#pragma unroll
  for (int i = 0; i < 8; ++i)
#pragma unroll
    for (int j = 0; j < 4; ++j) acc[i][j] = (f32x4){0.f, 0.f, 0.f, 0.f};

  const int lr = lane >> 3;               // row within 8-row DMA group
  const int sc8 = ((lane & 7) ^ lr) * 8;  // pre-swizzled source chunk (elems)
  const ushort_t* Abase = A + (size_t)(m0 + lr) * K + sc8;
  const ushort_t* Bbase = B + (size_t)(n0 + lr) * K + sc8;

  // half-tile stage: 128 rows of one matrix, 2 gld_lds per wave (16 rows/wave)
  auto stageA = [&](ushort_t* dst, int kt, int h) {
#pragma unroll
    for (int t = 0; t < 2; ++t) {
      const int r0 = h * 128 + w * 16 + t * 8;
      gld_lds16(Abase + (size_t)r0 * K + (size_t)kt * 64, &dst[r0 * 64]);
    }
  };
  auto stageB = [&](ushort_t* dst, int kt, int h) {
#pragma unroll
    for (int t = 0; t < 2; ++t) {
      const int r0 = h * 128 + w * 16 + t * 8;
      gld_lds16(Bbase + (size_t)r0 * K + (size_t)kt * 64, &dst[r0 * 64]);
    }
  };

  const int ntile = K >> 6;  // K=2048 -> 32 (even)

  // prologue: tile0 full into buf0 (8 loads), tile1 A-halves into buf1 (4 loads)
  stageA(As0, 0, 0); stageA(As0, 0, 1);
  stageB(Bs0, 0, 0); stageB(Bs0, 0, 1);
  if (ntile > 1) {
    stageA(As1, 1, 0); stageA(As1, 1, 1);
    asm volatile("s_waitcnt vmcnt(4)" ::: "memory");
  } else {
    asm volatile("s_waitcnt vmcnt(0)" ::: "memory");
  }
  __builtin_amdgcn_s_barrier();

  auto tileStep = [&](ushort_t* Asc, ushort_t* Bsc, ushort_t* Asn, ushort_t* Bsn, int ti) {
    const bool pf = (ti + 1 < ntile);
    GEMM_PHASE(Asc, Bsc, 0, 0, { if (pf) stageB(Bsn, ti + 1, 0); });
    GEMM_PHASE(Asc, Bsc, 0, 1, { if (pf) stageB(Bsn, ti + 1, 1); });
    GEMM_PHASE(Asc, Bsc, 1, 0, {});
    GEMM_PHASE(Asc, Bsc, 1, 1, {});
    // boundary: Asc's buffer is now free (all waves past the phase-3 barrier)
    if (ti + 2 < ntile) {
      stageA(Asc, ti + 2, 0);
      stageA(Asc, ti + 2, 1);
      asm volatile("s_waitcnt vmcnt(4)" ::: "memory");  // tile t+1 landed; t+2 A in flight
      __builtin_amdgcn_s_barrier();
    } else if (ti + 1 < ntile) {
      asm volatile("s_waitcnt vmcnt(0)" ::: "memory");  // final boundary: full drain once
      __builtin_amdgcn_s_barrier();
    }
  };

  for (int ti = 0; ti < ntile; ti += 2) {
    tileStep(As0, Bs0, As1, Bs1, ti);
    tileStep(As1, Bs1, As0, Bs0, ti + 1);
  }

#pragma unroll
  for (int mt = 0; mt < 8; ++mt)
#pragma unroll
    for (int nt = 0; nt < 4; ++nt)
#pragma unroll
      for (int r = 0; r < 4; ++r) {
        int row = m0 + wr + mt * 16 + quad * 4 + r;
        int col = n0 + wc + nt * 16 + m_l;
        float v = acc[mt][nt][r];
        if constexpr (__is_same(OutT, float)) C[(size_t)row * N + col] = v;
        else                                  C[(size_t)row * N + col] = f2b(v);
      }
}

// ---------- RMSNorm + RoPE in place on q,k parts of qkv [8192, 6144] ----------
// Q rows pre-scaled by (1/sqrt(128))*log2(e) for the max-free flash softmax.
__global__ void rmsrope(ushort_t* __restrict__ qkv, const float* __restrict__ freqs,
                        const float* __restrict__ wq, const float* __restrict__ wk) {
  int w = threadIdx.x >> 6, lane = threadIdx.x & 63;
  int rid = blockIdx.x * 4 + w;
  int h = rid & 15;
  int m = (rid >> 4) & 8191;
  int qk = rid >> 17;
  ushort_t* row = qkv + (size_t)m * 6144 + qk * 2048 + h * 128;
  uint32_t pr = *(const uint32_t*)(row + 2 * lane);
  float xr = b2f((ushort_t)(pr & 0xffff));
  float xi = b2f((ushort_t)(pr >> 16));
  float ss = xr * xr + xi * xi;
#pragma unroll
  for (int o = 1; o < 64; o <<= 1) ss += __shfl_xor(ss, o);
  float rinv = rsqrtf(ss * (1.f / 128.f) + 1e-5f);
  const float* wn = qk ? wk : wq;
  float nr = xr * rinv * wn[2 * lane];
  float ni = xi * rinv * wn[2 * lane + 1];
  float fc = freqs[(size_t)m * 128 + lane];
  float fs = freqs[(size_t)m * 128 + 64 + lane];
  float orr = nr * fc - ni * fs;
  float oii = nr * fs + ni * fc;
  const float k1 = 0.08838834764831845f * 1.4426950408889634f;
  float fscale = (qk == 0) ? k1 : 1.0f;  // qk is wave-uniform
  orr *= fscale;
  oii *= fscale;
  *(uint32_t*)(row + 2 * lane) = (uint32_t)f2b(orr) | ((uint32_t)f2b(oii) << 16);
}

// ---------- transpose V: qkv[m][4096+h*128+d] -> vt[bh][d][s] ----------
__global__ void transpose_v(const ushort_t* __restrict__ qkv, ushort_t* __restrict__ vt) {
  __shared__ ushort_t tile[64][136];
  int bh = blockIdx.y, s0 = blockIdx.x * 64;
  int b = bh >> 4, h = bh & 15;
  const ushort_t* src = qkv + (size_t)(b * 4096 + s0) * 6144 + 4096 + h * 128;
  int t = threadIdx.x;
  int r = t >> 2, c0 = (t & 3) * 32;
#pragma unroll
  for (int j = 0; j < 4; ++j)
    *(us8*)&tile[r][c0 + 8 * j] = *(const us8*)(src + (size_t)r * 6144 + c0 + 8 * j);
  __syncthreads();
  int d = t >> 1, sh = (t & 1) * 32;
  ushort_t* dst = vt + (size_t)bh * 524288 + (size_t)d * 4096 + s0 + sh;
#pragma unroll
  for (int i0 = 0; i0 < 32; i0 += 8) {
    us8 o;
#pragma unroll
    for (int j = 0; j < 8; ++j) o[j] = tile[sh + i0 + j][d];
    *(us8*)(dst + i0) = o;
  }
}

// ---------- flash attention: Br=128, Bc=64, 3-way KV split of S=4096 ----------
// Split ranges tile [0,4096) in Bc multiples: [0,1344) [1344,2688) [2688,4096)
// (21/21/22 iters). 3072 tiles = 12/CU = 4 even phases at residency 3.
// Max-free softmax => partials combine exactly: unnormalized O (bf16) + lsum
// (fp32, scattered into qkvb's dead V-cols). XCD-aware decode.
__global__ __launch_bounds__(256, 3) void flash_attn(const ushort_t* __restrict__ qkv,
                                                     const ushort_t* __restrict__ vt,
                                                     ushort_t* __restrict__ op0,
                                                     ushort_t* __restrict__ op1,
                                                     ushort_t* __restrict__ op2,
                                                     ushort_t* __restrict__ lbase) {
  __shared__ ushort_t Ks[64 * 128];   // row r, logical chunk c at r*128 + (c^s(r))*8
  __shared__ ushort_t VTs[128 * 64];  // row r, chunk c at r*64 + (c^(r&7))*8

  const int w = threadIdx.x >> 6, lane = threadIdx.x & 63;
  const int m_l = lane & 15, quad = lane >> 4;

  // XCD-aware tile decode (id%8 = XCD heuristic)
  const int id = blockIdx.x;
  const int xcd = id & 7, j = id >> 3;
  const int combo = xcd * 12 + (j >> 5);  // 0..95
  const int q0 = (j & 31) * 128;
  const int bh = combo & 31, split = combo >> 5;
  const int b = bh >> 4, h = bh & 15;
  const int kvbeg = split * 1344;
  const int kvend = (split == 2) ? 4096 : kvbeg + 1344;
  ushort_t* op = (split == 0) ? op0 : (split == 1) ? op1 : op2;

  const ushort_t* qb = qkv + (size_t)(b * 4096 + q0) * 6144 + h * 128;
  const ushort_t* kb = qkv + (size_t)(b * 4096) * 6144 + 2048 + h * 128;
  const ushort_t* vb = vt + (size_t)bh * 524288;

  const int lr = lane >> 4, p15 = lane & 15;

  // stage Q (two 64-row groups) through Ks; swizzle s(row)=row&3 | ((row>>3)&1)<<2 | ((row>>4)&1)<<3
  bf16x8 qf[2][4];
  const int rowq = w * 16 + m_l;
  const int sqr = (m_l & 3) | ((m_l >> 3) << 2) | ((w & 1) << 3);
#pragma unroll
  for (int g = 0; g < 2; ++g) {
    __syncthreads();
#pragma unroll
    for (int t = 0; t < 4; ++t) {
      int rbase = w * 16 + t * 4;
      int sst = lr | ((t >> 1) << 2) | ((w & 1) << 3);
      gld_lds16(qb + (size_t)(g * 64 + rbase + lr) * 6144 + (p15 ^ sst) * 8, &Ks[rbase * 128]);
    }
    __syncthreads();
#pragma unroll
    for (int kk = 0; kk < 4; ++kk)
      qf[g][kk] = __builtin_bit_cast(bf16x8,
          *(const us8*)&Ks[rowq * 128 + ((kk * 4 + quad) ^ sqr) * 8]);
  }

  // K-fragment rows for S^T mfma mt: kv(row m_l) = (m_l>>2)*8 + (m_l&3) + (mt&1)*4 + (mt>>1)*32
  int kbase[4];
#pragma unroll
  for (int mt = 0; mt < 4; ++mt)
    kbase[mt] = ((m_l >> 2) * 8 + (m_l & 3) + (mt & 1) * 4 + (mt >> 1) * 32) * 128;
  int cx[4];
#pragma unroll
  for (int kk = 0; kk < 4; ++kk) cx[kk] = ((kk * 4 + quad) ^ m_l) * 8;
  int vx[2];
#pragma unroll
  for (int kk = 0; kk < 2; ++kk) vx[kk] = ((kk * 4 + quad) ^ (m_l & 7)) * 8;

  f32x4 lacc[2] = {(f32x4){0.f, 0.f, 0.f, 0.f}, (f32x4){0.f, 0.f, 0.f, 0.f}};
  f32x4 Oa[2][8];
#pragma unroll
  for (int g = 0; g < 2; ++g)
#pragma unroll
    for (int nt = 0; nt < 8; ++nt) Oa[g][nt] = (f32x4){0.f, 0.f, 0.f, 0.f};

  for (int kv0 = kvbeg; kv0 < kvend; kv0 += 64) {
    __syncthreads();
    {
#pragma unroll
      for (int t = 0; t < 4; ++t) {
        int rbase = w * 16 + t * 4;
        int sst = lr | ((t >> 1) << 2) | ((w & 1) << 3);
        gld_lds16(kb + (size_t)(kv0 + rbase + lr) * 6144 + (p15 ^ sst) * 8, &Ks[rbase * 128]);
      }
      int lr2 = lane >> 3, s2 = (lane & 7) ^ lr2;
#pragma unroll
      for (int t = 0; t < 4; ++t) {
        int r = w * 32 + t * 8;
        gld_lds16(vb + (size_t)(r + lr2) * 4096 + kv0 + s2 * 8, &VTs[r * 64]);
      }
    }
    __syncthreads();

    // S^T[kv][q]: A = K rows (remapped), B = Q; each kf feeds both q groups
    f32x4 S[2][4];
#pragma unroll
    for (int g = 0; g < 2; ++g)
#pragma unroll
      for (int mt = 0; mt < 4; ++mt) S[g][mt] = (f32x4){0.f, 0.f, 0.f, 0.f};
    __builtin_amdgcn_s_setprio(1);
#pragma unroll
    for (int kk = 0; kk < 4; ++kk)
#pragma unroll
      for (int mt = 0; mt < 4; ++mt) {
        bf16x8 kf = __builtin_bit_cast(bf16x8, *(const us8*)&Ks[kbase[mt] + cx[kk]]);
        S[0][mt] = __builtin_amdgcn_mfma_f32_16x16x32_bf16(kf, qf[0][kk], S[0][mt], 0, 0, 0);
        S[1][mt] = __builtin_amdgcn_mfma_f32_16x16x32_bf16(kf, qf[1][kk], S[1][mt], 0, 0, 0);
      }
    __builtin_amdgcn_s_setprio(0);

    // max-free softmax + in-register pack to PV A-fragments
    union Upf { us8 u; bhalf2_t h[4]; } pf[2][2];
#pragma unroll
    for (int g = 0; g < 2; ++g) {
      f32x4 pe[4];
#pragma unroll
      for (int mt = 0; mt < 4; ++mt)
#pragma unroll
        for (int r = 0; r < 4; ++r)
          pe[mt][r] = __builtin_amdgcn_exp2f(S[g][mt][r]);
      lacc[g] += (pe[0] + pe[1]) + (pe[2] + pe[3]);
#pragma unroll
      for (int kk = 0; kk < 2; ++kk)
#pragma unroll
        for (int t = 0; t < 4; ++t) {
          int mt = kk * 2 + (t >> 1), r0 = (t & 1) * 2;
          f32x2 a = { pe[mt][r0], pe[mt][r0 + 1] };
          pf[g][kk].h[t] = __builtin_convertvector(a, bhalf2_t);
        }
    }

    // O += P.V; each vf feeds both q groups
    __builtin_amdgcn_s_setprio(1);
#pragma unroll
    for (int kk = 0; kk < 2; ++kk) {
      bf16x8 p0 = __builtin_bit_cast(bf16x8, pf[0][kk].u);
      bf16x8 p1 = __builtin_bit_cast(bf16x8, pf[1][kk].u);
#pragma unroll
      for (int nt = 0; nt < 8; ++nt) {
        bf16x8 vf = __builtin_bit_cast(bf16x8,
            *(const us8*)&VTs[(nt * 16 + m_l) * 64 + vx[kk]]);
        Oa[0][nt] = __builtin_amdgcn_mfma_f32_16x16x32_bf16(p0, vf, Oa[0][nt], 0, 0, 0);
        Oa[1][nt] = __builtin_amdgcn_mfma_f32_16x16x32_bf16(p1, vf, Oa[1][nt], 0, 0, 0);
      }
    }
    __builtin_amdgcn_s_setprio(0);
  }

  // epilogue per q group: write UNNORMALIZED partial O + lsum
#pragma unroll
  for (int g = 0; g < 2; ++g) {
    float lsum = (lacc[g][0] + lacc[g][1]) + (lacc[g][2] + lacc[g][3]);
    lsum += __shfl_xor(lsum, 16);
    lsum += __shfl_xor(lsum, 32);
    if (quad == 0) {  // lane m_l owns q-row = m_l of this (w,g) 16-group
      int s = q0 + g * 64 + w * 16 + m_l;
      *(float*)(lbase + (size_t)(b * 4096 + s) * 6144 + 4096 + h * 128 + split * 2) = lsum;
    }
#pragma unroll
    for (int r = 0; r < 4; ++r) {
      int s = q0 + g * 64 + w * 16 + quad * 4 + r;
      ushort_t* dst = op + (size_t)(b * 4096 + s) * 2048 + h * 128;
#pragma unroll
      for (int nt = 0; nt < 8; ++nt) dst[nt * 16 + m_l] = f2b(Oa[g][nt][r]);
    }
  }
}

// ---------- combine: ctx = (p0+p1+p2)/(l0+l1+l2), in place on p0 ----------
__global__ void combine_splits(ushort_t* __restrict__ p0, const ushort_t* __restrict__ p1,
                               const ushort_t* __restrict__ p2, const ushort_t* __restrict__ lbase) {
  int tid = blockIdx.x * 256 + threadIdx.x;  // 2,097,152 threads, 8 elems each
  int row = tid >> 4;                        // (b*4096+s)*16 + h
  int brow = row >> 4, h = row & 15;
  const float* lp = (const float*)(lbase + (size_t)brow * 6144 + 4096 + h * 128);
  float inv = 1.f / (lp[0] + lp[1] + lp[2]);
  size_t off = (size_t)tid * 8;
  us8 a = *(const us8*)(p0 + off);
  us8 bb = *(const us8*)(p1 + off);
  us8 c = *(const us8*)(p2 + off);
  us8 o;
#pragma unroll
  for (int i = 0; i < 8; ++i)
    o[i] = f2b((b2f(a[i]) + b2f(bb[i]) + b2f(c[i])) * inv);
  *(us8*)(p0 + off) = o;
}

extern "C" void kernel_launch(void* const* d_in, const int* in_sizes, int n_in,
                              void* d_out, int out_size, void* d_ws, size_t ws_size,
                              hipStream_t stream) {
  const float* x     = (const float*)d_in[0];
  const float* freqs = (const float*)d_in[1];
  const float* wq    = (const float*)d_in[2];
  const float* wk    = (const float*)d_in[3];
  const float* wv    = (const float*)d_in[4];
  const float* wo    = (const float*)d_in[5];
  const float* nqw   = (const float*)d_in[6];
  const float* nkw   = (const float*)d_in[7];
  float* out = (float*)d_out;

  char* ws = (char*)d_ws;
  ushort_t* xb    = (ushort_t*)(ws);                 // 8192x2048 bf16 (32 MB); later: flash partial1, then wo bf16
  ushort_t* wqkvb = (ushort_t*)(ws + 33554432);      // 6144x2048 bf16 (24 MB + 8 MB slack); later: flash partial2
  ushort_t* qkvb  = (ushort_t*)(ws + 67108864);      // 8192x6144 bf16 (96 MB); V-cols recycled for lsums
  ushort_t* vtb   = (ushort_t*)(ws + 167772160);     // 32x128x4096 bf16 (32 MB)
  ushort_t* ctxb  = (ushort_t*)(ws + 201326592);     // 8192x2048 bf16 (32 MB); flash partial0 -> ctx
  ushort_t* part2 = wqkvb;                           // 32 MB contiguous (wqkvb + slack region)
  ushort_t* wob2  = xb;                              // wo bf16, cast after combine frees xb
  if (ws_size < 234881024) { fprintf(stderr, "kernel_launch: ws too small (%zu < 234881024)\n", ws_size); return; }

  cast_f2b<<<16384, 256, 0, stream>>>(x, xb, 4194304);
  cast3_f2b<<<12288, 256, 0, stream>>>(wq, wk, wv, wqkvb);

  gemm_bt<ushort_t><<<dim3(24, 32), 512, 0, stream>>>(xb, wqkvb, qkvb, 8192, 6144, 2048);
  rmsrope<<<65536, 256, 0, stream>>>(qkvb, freqs, nqw, nkw);
  transpose_v<<<dim3(64, 32), 256, 0, stream>>>(qkvb, vtb);
  flash_attn<<<3072, 256, 0, stream>>>(qkvb, vtb, ctxb, xb, part2, qkvb);
  combine_splits<<<8192, 256, 0, stream>>>(ctxb, xb, part2, qkvb);
  cast_f2b<<<4096, 256, 0, stream>>>(wo, wob2, 1048576);
  gemm_bt<float><<<dim3(8, 32), 512, 0, stream>>>(ctxb, wob2, out, 8192, 2048, 2048);
}

// Round 6
// 751.178 us; speedup vs baseline: 1.0720x; 1.0720x over previous
//
#include <hip/hip_runtime.h>
#include <hip/hip_bf16.h>
#include <cstdint>
#include <cstdio>

typedef unsigned short ushort_t;
typedef __attribute__((ext_vector_type(8))) __bf16 bf16x8;
typedef __attribute__((ext_vector_type(2))) __bf16 bhalf2_t;
typedef __attribute__((ext_vector_type(8))) unsigned short us8;
typedef __attribute__((ext_vector_type(4))) unsigned short us4;
typedef __attribute__((ext_vector_type(4))) float f32x4;
typedef __attribute__((ext_vector_type(2))) float f32x2;

__device__ __forceinline__ ushort_t f2b(float f) {
  uint32_t u = __builtin_bit_cast(uint32_t, f);
  uint32_t r = (u + 0x7fffu + ((u >> 16) & 1u)) >> 16;  // RNE
  return (ushort_t)r;
}
__device__ __forceinline__ float b2f(ushort_t s) {
  return __builtin_bit_cast(float, (uint32_t)s << 16);
}

// async global->LDS, 16B per lane; LDS dest = wave-uniform base + lane*16
__device__ __forceinline__ void gld_lds16(const void* g, void* l) {
  __builtin_amdgcn_global_load_lds(
      (__attribute__((address_space(1))) void*)(uintptr_t)g,
      (__attribute__((address_space(3))) void*)(uint32_t)(uintptr_t)l,
      16, 0, 0);
}

// ---------- cast fp32 -> bf16, 4 elems/thread ----------
__global__ void cast_f2b(const float* __restrict__ src, ushort_t* __restrict__ dst, int n4) {
  int i = blockIdx.x * 256 + threadIdx.x;
  if (i < n4) {
    float4 f = ((const float4*)src)[i];
    us4 o = { f2b(f.x), f2b(f.y), f2b(f.z), f2b(f.w) };
    ((us4*)dst)[i] = o;
  }
}

// ---------- cast 3 weight matrices (wq,wk,wv) into contiguous dst ----------
__global__ void cast3_f2b(const float* __restrict__ a, const float* __restrict__ b,
                          const float* __restrict__ c, ushort_t* __restrict__ dst) {
  int i = blockIdx.x * 256 + threadIdx.x;  // float4 index, 3*1048576 total
  int seg = i >> 20, local = i & 1048575;
  const float* src = (seg == 0) ? a : (seg == 1) ? b : c;
  float4 f = ((const float4*)src)[local];
  us4 o = { f2b(f.x), f2b(f.y), f2b(f.z), f2b(f.w) };
  ((us4*)dst)[i] = o;
}

// ---------- GEMM: C[m,n] = sum_k A[m,k]*B[n,k]; A:[M,K] B:[N,K] row-major bf16 ----------
// 256x256 tile, BK=64, 8 waves (2Mx4N), double-buffered LDS (128 KiB, 1 block/CU).
// Gray-code quadrant schedule: (0,0)->(0,1)->(1,1)->(1,0) with PERSISTENT
// fragments: 24 ds_read_b128 / 64 MFMA per K-tile per wave (6 B/lane/MFMA =
// ~96 B/cyc LDS demand, under the 128 B/cyc peak). Previous schedule re-read
// A and B per quadrant (12 B/lane/MFMA = 192 B/cyc demand) and was LDS-bound.
// Counted-vmcnt DMA pipeline (verified r2/r3 ledger): B(t+1) halves issued in
// ph0/ph1, A(t+2) at boundary into freed buffer, s_waitcnt vmcnt(4) keeps one
// half-tile in flight across every barrier. Chunk-XOR swizzle (T2) unchanged.
#define LOAD_AH(AF, MH)                                                              \
  _Pragma("unroll")                                                                  \
  for (int kk = 0; kk < 2; ++kk) {                                                   \
    const int cx = ((kk * 4 + quad) ^ (m_l & 7)) * 8;                                \
    _Pragma("unroll")                                                                \
    for (int mt = 0; mt < 4; ++mt)                                                   \
      AF[kk][mt] = __builtin_bit_cast(bf16x8,                                        \
          *(const us8*)&Asc[(wr + ((MH) * 4 + mt) * 16 + m_l) * 64 + cx]);           \
  }
#define LOAD_BH(BF, NH)                                                              \
  _Pragma("unroll")                                                                  \
  for (int kk = 0; kk < 2; ++kk) {                                                   \
    const int cx = ((kk * 4 + quad) ^ (m_l & 7)) * 8;                                \
    _Pragma("unroll")                                                                \
    for (int nt = 0; nt < 2; ++nt)                                                   \
      BF[kk][nt] = __builtin_bit_cast(bf16x8,                                        \
          *(const us8*)&Bsc[(wc + ((NH) * 2 + nt) * 16 + m_l) * 64 + cx]);           \
  }
#define MFMA_QUAD(AF, BF, MH, NH)                                                    \
  _Pragma("unroll")                                                                  \
  for (int kk = 0; kk < 2; ++kk)                                                     \
    _Pragma("unroll")                                                                \
    for (int mt = 0; mt < 4; ++mt)                                                   \
      _Pragma("unroll")                                                              \
      for (int nt = 0; nt < 2; ++nt)                                                 \
        acc[(MH) * 4 + mt][(NH) * 2 + nt] = __builtin_amdgcn_mfma_f32_16x16x32_bf16( \
            AF[kk][mt], BF[kk][nt], acc[(MH) * 4 + mt][(NH) * 2 + nt], 0, 0, 0);

template <typename OutT>
__global__ __launch_bounds__(512, 2) void gemm_bt(const ushort_t* __restrict__ A,
                                                  const ushort_t* __restrict__ B,
                                                  OutT* __restrict__ C,
                                                  int M, int N, int K) {
  __shared__ ushort_t As0[256 * 64], As1[256 * 64];
  __shared__ ushort_t Bs0[256 * 64], Bs1[256 * 64];
  const int w    = threadIdx.x >> 6;
  const int lane = threadIdx.x & 63;
  const int m_l  = lane & 15;
  const int quad = lane >> 4;
  const int m0 = blockIdx.y * 256, n0 = blockIdx.x * 256;
  const int wr = (w >> 2) * 128, wc = (w & 3) * 64;  // per-wave 128x64 output

  f32x4 acc[8][4];
#pragma unroll
  for (int i = 0; i < 8; ++i)
#pragma unroll
    for (int j = 0; j < 4; ++j) acc[i][j] = (f32x4){0.f, 0.f, 0.f, 0.f};

  const int lr = lane >> 3;               // row within 8-row DMA group
  const int sc8 = ((lane & 7) ^ lr) * 8;  // pre-swizzled source chunk (elems)
  const ushort_t* Abase = A + (size_t)(m0 + lr) * K + sc8;
  const ushort_t* Bbase = B + (size_t)(n0 + lr) * K + sc8;

  // half-tile stage: 128 rows of one matrix, 2 gld_lds per wave (16 rows/wave)
  auto stageA = [&](ushort_t* dst, int kt, int h) {
#pragma unroll
    for (int t = 0; t < 2; ++t) {
      const int r0 = h * 128 + w * 16 + t * 8;
      gld_lds16(Abase + (size_t)r0 * K + (size_t)kt * 64, &dst[r0 * 64]);
    }
  };
  auto stageB = [&](ushort_t* dst, int kt, int h) {
#pragma unroll
    for (int t = 0; t < 2; ++t) {
      const int r0 = h * 128 + w * 16 + t * 8;
      gld_lds16(Bbase + (size_t)r0 * K + (size_t)kt * 64, &dst[r0 * 64]);
    }
  };

  const int ntile = K >> 6;  // K=2048 -> 32 (even)

  // prologue: tile0 full into buf0 (8 loads), tile1 A-halves into buf1 (4 loads)
  stageA(As0, 0, 0); stageA(As0, 0, 1);
  stageB(Bs0, 0, 0); stageB(Bs0, 0, 1);
  if (ntile > 1) {
    stageA(As1, 1, 0); stageA(As1, 1, 1);
    asm volatile("s_waitcnt vmcnt(4)" ::: "memory");
  } else {
    asm volatile("s_waitcnt vmcnt(0)" ::: "memory");
  }
  __builtin_amdgcn_s_barrier();

  auto tileStep = [&](const ushort_t* Asc, const ushort_t* Bsc,
                      ushort_t* Asn, ushort_t* Bsn, int ti) {
    const bool pf = (ti + 1 < ntile);
    bf16x8 Af[2][4], Bf0[2][2], Bf1[2][2];
    // ph0: A-half0 + B-half0 reads; stage B(t+1) h0; quad (0,0)
    LOAD_AH(Af, 0)
    LOAD_BH(Bf0, 0)
    if (pf) stageB(Bsn, ti + 1, 0);
    __builtin_amdgcn_s_barrier();
    __builtin_amdgcn_s_setprio(1);
    MFMA_QUAD(Af, Bf0, 0, 0)
    __builtin_amdgcn_s_setprio(0);
    __builtin_amdgcn_s_barrier();
    // ph1: B-half1 reads; stage B(t+1) h1; quad (0,1)
    LOAD_BH(Bf1, 1)
    if (pf) stageB(Bsn, ti + 1, 1);
    __builtin_amdgcn_s_barrier();
    __builtin_amdgcn_s_setprio(1);
    MFMA_QUAD(Af, Bf1, 0, 1)
    __builtin_amdgcn_s_setprio(0);
    __builtin_amdgcn_s_barrier();
    // ph2: A-half1 reads (overwrite Af); quads (1,1) then (1,0)
    LOAD_AH(Af, 1)
    __builtin_amdgcn_s_barrier();
    __builtin_amdgcn_s_setprio(1);
    MFMA_QUAD(Af, Bf1, 1, 1)
    MFMA_QUAD(Af, Bf0, 1, 0)
    __builtin_amdgcn_s_setprio(0);
    __builtin_amdgcn_s_barrier();
    // boundary: Asc's buffer is free; stage A(t+2) into it
    if (ti + 2 < ntile) {
      stageA((ushort_t*)Asc, ti + 2, 0);
      stageA((ushort_t*)Asc, ti + 2, 1);
      asm volatile("s_waitcnt vmcnt(4)" ::: "memory");  // tile t+1 landed; t+2 A in flight
      __builtin_amdgcn_s_barrier();
    } else if (ti + 1 < ntile) {
      asm volatile("s_waitcnt vmcnt(0)" ::: "memory");  // final boundary: full drain once
      __builtin_amdgcn_s_barrier();
    }
  };

  for (int ti = 0; ti < ntile; ti += 2) {
    tileStep(As0, Bs0, As1, Bs1, ti);
    tileStep(As1, Bs1, As0, Bs0, ti + 1);
  }

#pragma unroll
  for (int mt = 0; mt < 8; ++mt)
#pragma unroll
    for (int nt = 0; nt < 4; ++nt)
#pragma unroll
      for (int r = 0; r < 4; ++r) {
        int row = m0 + wr + mt * 16 + quad * 4 + r;
        int col = n0 + wc + nt * 16 + m_l;
        float v = acc[mt][nt][r];
        if constexpr (__is_same(OutT, float)) C[(size_t)row * N + col] = v;
        else                                  C[(size_t)row * N + col] = f2b(v);
      }
}

// ---------- RMSNorm + RoPE in place on q,k parts of qkv [8192, 6144] ----------
// Q rows pre-scaled by (1/sqrt(128))*log2(e) for the max-free flash softmax.
__global__ void rmsrope(ushort_t* __restrict__ qkv, const float* __restrict__ freqs,
                        const float* __restrict__ wq, const float* __restrict__ wk) {
  int w = threadIdx.x >> 6, lane = threadIdx.x & 63;
  int rid = blockIdx.x * 4 + w;
  int h = rid & 15;
  int m = (rid >> 4) & 8191;
  int qk = rid >> 17;
  ushort_t* row = qkv + (size_t)m * 6144 + qk * 2048 + h * 128;
  uint32_t pr = *(const uint32_t*)(row + 2 * lane);
  float xr = b2f((ushort_t)(pr & 0xffff));
  float xi = b2f((ushort_t)(pr >> 16));
  float ss = xr * xr + xi * xi;
#pragma unroll
  for (int o = 1; o < 64; o <<= 1) ss += __shfl_xor(ss, o);
  float rinv = rsqrtf(ss * (1.f / 128.f) + 1e-5f);
  const float* wn = qk ? wk : wq;
  float nr = xr * rinv * wn[2 * lane];
  float ni = xi * rinv * wn[2 * lane + 1];
  float fc = freqs[(size_t)m * 128 + lane];
  float fs = freqs[(size_t)m * 128 + 64 + lane];
  float orr = nr * fc - ni * fs;
  float oii = nr * fs + ni * fc;
  const float k1 = 0.08838834764831845f * 1.4426950408889634f;
  float fscale = (qk == 0) ? k1 : 1.0f;  // qk is wave-uniform
  orr *= fscale;
  oii *= fscale;
  *(uint32_t*)(row + 2 * lane) = (uint32_t)f2b(orr) | ((uint32_t)f2b(oii) << 16);
}

// ---------- transpose V: qkv[m][4096+h*128+d] -> vt[bh][d][s] ----------
__global__ void transpose_v(const ushort_t* __restrict__ qkv, ushort_t* __restrict__ vt) {
  __shared__ ushort_t tile[64][136];
  int bh = blockIdx.y, s0 = blockIdx.x * 64;
  int b = bh >> 4, h = bh & 15;
  const ushort_t* src = qkv + (size_t)(b * 4096 + s0) * 6144 + 4096 + h * 128;
  int t = threadIdx.x;
  int r = t >> 2, c0 = (t & 3) * 32;
#pragma unroll
  for (int j = 0; j < 4; ++j)
    *(us8*)&tile[r][c0 + 8 * j] = *(const us8*)(src + (size_t)r * 6144 + c0 + 8 * j);
  __syncthreads();
  int d = t >> 1, sh = (t & 1) * 32;
  ushort_t* dst = vt + (size_t)bh * 524288 + (size_t)d * 4096 + s0 + sh;
#pragma unroll
  for (int i0 = 0; i0 < 32; i0 += 8) {
    us8 o;
#pragma unroll
    for (int j = 0; j < 8; ++j) o[j] = tile[sh + i0 + j][d];
    *(us8*)(dst + i0) = o;
  }
}

// ---------- flash attention: Br=128, Bc=64, 3-way KV split of S=4096 ----------
// Split ranges tile [0,4096) in Bc multiples: [0,1344) [1344,2688) [2688,4096)
// (21/21/22 iters). 3072 tiles = 6/CU at residency 2 = 6 even phases.
// K/V double-buffered in LDS (64 KB): tile t+1's 8 gld_lds issued at top of
// iter t, counted s_waitcnt vmcnt(8) (tile t landed, t+1 in flight) — the
// staging latency that was serially exposed per tile now hides under compute.
// Max-free softmax => partials combine exactly: unnormalized O (bf16) + lsum
// (fp32, scattered into qkvb's dead V-cols). XCD-aware decode.
__global__ __launch_bounds__(256, 2) void flash_attn(const ushort_t* __restrict__ qkv,
                                                     const ushort_t* __restrict__ vt,
                                                     ushort_t* __restrict__ op0,
                                                     ushort_t* __restrict__ op1,
                                                     ushort_t* __restrict__ op2,
                                                     ushort_t* __restrict__ lbase) {
  __shared__ ushort_t Ks[2 * 64 * 128];   // buf b at b*8192; row r, chunk c at r*128 + (c^s(r))*8
  __shared__ ushort_t VTs[2 * 128 * 64];  // buf b at b*8192; row r, chunk c at r*64 + (c^(r&7))*8

  const int w = threadIdx.x >> 6, lane = threadIdx.x & 63;
  const int m_l = lane & 15, quad = lane >> 4;

  // XCD-aware tile decode (id%8 = XCD heuristic)
  const int id = blockIdx.x;
  const int xcd = id & 7, j = id >> 3;
  const int combo = xcd * 12 + (j >> 5);  // 0..95
  const int q0 = (j & 31) * 128;
  const int bh = combo & 31, split = combo >> 5;
  const int b = bh >> 4, h = bh & 15;
  const int kvbeg = split * 1344;
  const int kvend = (split == 2) ? 4096 : kvbeg + 1344;
  ushort_t* op = (split == 0) ? op0 : (split == 1) ? op1 : op2;

  const ushort_t* qb = qkv + (size_t)(b * 4096 + q0) * 6144 + h * 128;
  const ushort_t* kb = qkv + (size_t)(b * 4096) * 6144 + 2048 + h * 128;
  const ushort_t* vb = vt + (size_t)bh * 524288;

  const int lr = lane >> 4, p15 = lane & 15;

  // stage Q (two 64-row groups) through Ks buf0; swizzle s(row)=row&3 | ((row>>3)&1)<<2 | ((row>>4)&1)<<3
  bf16x8 qf[2][4];
  const int rowq = w * 16 + m_l;
  const int sqr = (m_l & 3) | ((m_l >> 3) << 2) | ((w & 1) << 3);
#pragma unroll
  for (int g = 0; g < 2; ++g) {
    __syncthreads();
#pragma unroll
    for (int t = 0; t < 4; ++t) {
      int rbase = w * 16 + t * 4;
      int sst = lr | ((t >> 1) << 2) | ((w & 1) << 3);
      gld_lds16(qb + (size_t)(g * 64 + rbase + lr) * 6144 + (p15 ^ sst) * 8, &Ks[rbase * 128]);
    }
    __syncthreads();
#pragma unroll
    for (int kk = 0; kk < 4; ++kk)
      qf[g][kk] = __builtin_bit_cast(bf16x8,
          *(const us8*)&Ks[rowq * 128 + ((kk * 4 + quad) ^ sqr) * 8]);
  }
  __syncthreads();  // drain lgkm: qf reads done before DMA overwrites buf0

  // K-fragment rows for S^T mfma mt: kv(row m_l) = (m_l>>2)*8 + (m_l&3) + (mt&1)*4 + (mt>>1)*32
  int kbase[4];
#pragma unroll
  for (int mt = 0; mt < 4; ++mt)
    kbase[mt] = ((m_l >> 2) * 8 + (m_l & 3) + (mt & 1) * 4 + (mt >> 1) * 32) * 128;
  int cx[4];
#pragma unroll
  for (int kk = 0; kk < 4; ++kk) cx[kk] = ((kk * 4 + quad) ^ m_l) * 8;
  int vx[2];
#pragma unroll
  for (int kk = 0; kk < 2; ++kk) vx[kk] = ((kk * 4 + quad) ^ (m_l & 7)) * 8;

  // per-tile K/V DMA: 8 loads/wave (4 K + 4 V) into buffer at element offset bo
  auto issueKV = [&](int kv0, int bo) {
#pragma unroll
    for (int t = 0; t < 4; ++t) {
      int rbase = w * 16 + t * 4;
      int sst = lr | ((t >> 1) << 2) | ((w & 1) << 3);
      gld_lds16(kb + (size_t)(kv0 + rbase + lr) * 6144 + (p15 ^ sst) * 8, &Ks[bo + rbase * 128]);
    }
    int lr2 = lane >> 3, s2 = (lane & 7) ^ lr2;
#pragma unroll
    for (int t = 0; t < 4; ++t) {
      int r = w * 32 + t * 8;
      gld_lds16(vb + (size_t)(r + lr2) * 4096 + kv0 + s2 * 8, &VTs[bo + r * 64]);
    }
  };

  f32x4 lacc[2] = {(f32x4){0.f, 0.f, 0.f, 0.f}, (f32x4){0.f, 0.f, 0.f, 0.f}};
  f32x4 Oa[2][8];
#pragma unroll
  for (int g = 0; g < 2; ++g)
#pragma unroll
    for (int nt = 0; nt < 8; ++nt) Oa[g][nt] = (f32x4){0.f, 0.f, 0.f, 0.f};

  const int nit = (kvend - kvbeg) >> 6;
  issueKV(kvbeg, 0);  // prologue: tile 0 -> buf0

  for (int it = 0; it < nit; ++it) {
    const int kv0 = kvbeg + it * 64;
    const int bo = (it & 1) << 13;  // current buffer (elements)
    if (it + 1 < nit) {
      issueKV(kv0 + 64, bo ^ 8192);                     // prefetch t+1 into other buf
      asm volatile("s_waitcnt vmcnt(8)" ::: "memory");  // tile t landed; t+1 in flight
    } else {
      asm volatile("s_waitcnt vmcnt(0)" ::: "memory");
    }
    __builtin_amdgcn_s_barrier();

    // S^T[kv][q]: A = K rows (remapped), B = Q; each kf feeds both q groups
    f32x4 S[2][4];
#pragma unroll
    for (int g = 0; g < 2; ++g)
#pragma unroll
      for (int mt = 0; mt < 4; ++mt) S[g][mt] = (f32x4){0.f, 0.f, 0.f, 0.f};
    __builtin_amdgcn_s_setprio(1);
#pragma unroll
    for (int kk = 0; kk < 4; ++kk)
#pragma unroll
      for (int mt = 0; mt < 4; ++mt) {
        bf16x8 kf = __builtin_bit_cast(bf16x8, *(const us8*)&Ks[bo + kbase[mt] + cx[kk]]);
        S[0][mt] = __builtin_amdgcn_mfma_f32_16x16x32_bf16(kf, qf[0][kk], S[0][mt], 0, 0, 0);
        S[1][mt] = __builtin_amdgcn_mfma_f32_16x16x32_bf16(kf, qf[1][kk], S[1][mt], 0, 0, 0);
      }
    __builtin_amdgcn_s_setprio(0);

    // max-free softmax + in-register pack to PV A-fragments
    union Upf { us8 u; bhalf2_t h[4]; } pf[2][2];
#pragma unroll
    for (int g = 0; g < 2; ++g) {
      f32x4 pe[4];
#pragma unroll
      for (int mt = 0; mt < 4; ++mt)
#pragma unroll
        for (int r = 0; r < 4; ++r)
          pe[mt][r] = __builtin_amdgcn_exp2f(S[g][mt][r]);
      lacc[g] += (pe[0] + pe[1]) + (pe[2] + pe[3]);
#pragma unroll
      for (int kk = 0; kk < 2; ++kk)
#pragma unroll
        for (int t = 0; t < 4; ++t) {
          int mt = kk * 2 + (t >> 1), r0 = (t & 1) * 2;
          f32x2 a = { pe[mt][r0], pe[mt][r0 + 1] };
          pf[g][kk].h[t] = __builtin_convertvector(a, bhalf2_t);
        }
    }

    // O += P.V; each vf feeds both q groups
    __builtin_amdgcn_s_setprio(1);
#pragma unroll
    for (int kk = 0; kk < 2; ++kk) {
      bf16x8 p0 = __builtin_bit_cast(bf16x8, pf[0][kk].u);
      bf16x8 p1 = __builtin_bit_cast(bf16x8, pf[1][kk].u);
#pragma unroll
      for (int nt = 0; nt < 8; ++nt) {
        bf16x8 vf = __builtin_bit_cast(bf16x8,
            *(const us8*)&VTs[bo + (nt * 16 + m_l) * 64 + vx[kk]]);
        Oa[0][nt] = __builtin_amdgcn_mfma_f32_16x16x32_bf16(p0, vf, Oa[0][nt], 0, 0, 0);
        Oa[1][nt] = __builtin_amdgcn_mfma_f32_16x16x32_bf16(p1, vf, Oa[1][nt], 0, 0, 0);
      }
    }
    __builtin_amdgcn_s_setprio(0);
    __builtin_amdgcn_s_barrier();  // all reads of this buf done before it is re-targeted
  }

  // epilogue per q group: write UNNORMALIZED partial O + lsum
#pragma unroll
  for (int g = 0; g < 2; ++g) {
    float lsum = (lacc[g][0] + lacc[g][1]) + (lacc[g][2] + lacc[g][3]);
    lsum += __shfl_xor(lsum, 16);
    lsum += __shfl_xor(lsum, 32);
    if (quad == 0) {  // lane m_l owns q-row = m_l of this (w,g) 16-group
      int s = q0 + g * 64 + w * 16 + m_l;
      *(float*)(lbase + (size_t)(b * 4096 + s) * 6144 + 4096 + h * 128 + split * 2) = lsum;
    }
#pragma unroll
    for (int r = 0; r < 4; ++r) {
      int s = q0 + g * 64 + w * 16 + quad * 4 + r;
      ushort_t* dst = op + (size_t)(b * 4096 + s) * 2048 + h * 128;
#pragma unroll
      for (int nt = 0; nt < 8; ++nt) dst[nt * 16 + m_l] = f2b(Oa[g][nt][r]);
    }
  }
}

// ---------- combine: ctx = (p0+p1+p2)/(l0+l1+l2), in place on p0 ----------
__global__ void combine_splits(ushort_t* __restrict__ p0, const ushort_t* __restrict__ p1,
                               const ushort_t* __restrict__ p2, const ushort_t* __restrict__ lbase) {
  int tid = blockIdx.x * 256 + threadIdx.x;  // 2,097,152 threads, 8 elems each
  int row = tid >> 4;                        // (b*4096+s)*16 + h
  int brow = row >> 4, h = row & 15;
  const float* lp = (const float*)(lbase + (size_t)brow * 6144 + 4096 + h * 128);
  float inv = 1.f / (lp[0] + lp[1] + lp[2]);
  size_t off = (size_t)tid * 8;
  us8 a = *(const us8*)(p0 + off);
  us8 bb = *(const us8*)(p1 + off);
  us8 c = *(const us8*)(p2 + off);
  us8 o;
#pragma unroll
  for (int i = 0; i < 8; ++i)
    o[i] = f2b((b2f(a[i]) + b2f(bb[i]) + b2f(c[i])) * inv);
  *(us8*)(p0 + off) = o;
}

extern "C" void kernel_launch(void* const* d_in, const int* in_sizes, int n_in,
                              void* d_out, int out_size, void* d_ws, size_t ws_size,
                              hipStream_t stream) {
  const float* x     = (const float*)d_in[0];
  const float* freqs = (const float*)d_in[1];
  const float* wq    = (const float*)d_in[2];
  const float* wk    = (const float*)d_in[3];
  const float* wv    = (const float*)d_in[4];
  const float* wo    = (const float*)d_in[5];
  const float* nqw   = (const float*)d_in[6];
  const float* nkw   = (const float*)d_in[7];
  float* out = (float*)d_out;

  char* ws = (char*)d_ws;
  ushort_t* xb    = (ushort_t*)(ws);                 // 8192x2048 bf16 (32 MB); later: flash partial1, then wo bf16
  ushort_t* wqkvb = (ushort_t*)(ws + 33554432);      // 6144x2048 bf16 (24 MB + 8 MB slack); later: flash partial2
  ushort_t* qkvb  = (ushort_t*)(ws + 67108864);      // 8192x6144 bf16 (96 MB); V-cols recycled for lsums
  ushort_t* vtb   = (ushort_t*)(ws + 167772160);     // 32x128x4096 bf16 (32 MB)
  ushort_t* ctxb  = (ushort_t*)(ws + 201326592);     // 8192x2048 bf16 (32 MB); flash partial0 -> ctx
  ushort_t* part2 = wqkvb;                           // 32 MB contiguous (wqkvb + slack region)
  ushort_t* wob2  = xb;                              // wo bf16, cast after combine frees xb
  if (ws_size < 234881024) { fprintf(stderr, "kernel_launch: ws too small (%zu < 234881024)\n", ws_size); return; }

  cast_f2b<<<16384, 256, 0, stream>>>(x, xb, 4194304);
  cast3_f2b<<<12288, 256, 0, stream>>>(wq, wk, wv, wqkvb);

  gemm_bt<ushort_t><<<dim3(24, 32), 512, 0, stream>>>(xb, wqkvb, qkvb, 8192, 6144, 2048);
  rmsrope<<<65536, 256, 0, stream>>>(qkvb, freqs, nqw, nkw);
  transpose_v<<<dim3(64, 32), 256, 0, stream>>>(qkvb, vtb);
  flash_attn<<<3072, 256, 0, stream>>>(qkvb, vtb, ctxb, xb, part2, qkvb);
  combine_splits<<<8192, 256, 0, stream>>>(ctxb, xb, part2, qkvb);
  cast_f2b<<<4096, 256, 0, stream>>>(wo, wob2, 1048576);
  gemm_bt<float><<<dim3(8, 32), 512, 0, stream>>>(ctxb, wob2, out, 8192, 2048, 2048);
}